// Round 9
// baseline (308.121 us; speedup 1.0000x reference)
//
#include <hip/hip_runtime.h>
#include <math.h>

typedef _Float16 f16_t;
typedef _Float16 f16x8 __attribute__((ext_vector_type(8)));
typedef _Float16 f16x4 __attribute__((ext_vector_type(4)));
typedef _Float16 f16x2 __attribute__((ext_vector_type(2)));
typedef __fp16 h16x2 __attribute__((ext_vector_type(2)));
typedef float f32x4 __attribute__((ext_vector_type(4)));

// fp32 -> fp16 weights into d_ws in MFMA A-fragment-linear order:
// frag element (kc, nt, lane, j) = W[nt*16 + (lane&15)][kc*32 + (lane>>4)*8 + j]
// stored at ((kc*16 + nt)*64 + lane)*8 + j  -> a wave's A-frag load is lane-contiguous
// 16 B/lane (perfectly coalesced global_load_dwordx4, L2-resident).
// W1 (kc 0..3) at 0 (32768 elems); W2 (kc 0..7) at 32768 (65536 elems).
__global__ void wconv(const float* __restrict__ W1, const float* __restrict__ W2,
                      f16_t* __restrict__ o) {
  int i = blockIdx.x * 256 + threadIdx.x;  // 0..65535
  if (i < 32768) {
    int n = i >> 7, k = i & 127;
    int kc = k >> 5, q = (k >> 3) & 3, j = k & 7;
    int nt = n >> 4, c = n & 15;
    o[((kc * 16 + nt) * 64 + q * 16 + c) * 8 + j] = (f16_t)W1[i];
  }
  {
    int n = i >> 8, k = i & 255;
    int kc = k >> 5, q = (k >> 3) & 3, j = k & 7;
    int nt = n >> 4, c = n & 15;
    o[32768 + ((kc * 16 + nt) * 64 + q * 16 + c) * 8 + j] = (f16_t)W2[i];
  }
}

__device__ __forceinline__ f16x2 pk2(float a, float b) {
  union { h16x2 h; f16x2 f; } u;
  u.h = __builtin_amdgcn_cvt_pkrtz(a, b);
  return u.f;
}

#define COMP(v, r) ((r) == 0 ? (v).x : (r) == 1 ? (v).y : (r) == 2 ? (v).z : (v).w)

// Transposed fused MLP: D[feat][edge] = W @ x^T. Tile = 128 edges, 512 threads,
// 8 waves = 4 feat-rows (64 feats) x 2 edge-cols (64 edges); wave tile 64f x 64e,
// acc[4][4] = 64 VGPR. Weights stream global(L2)->VGPR (fragment-linear, coalesced);
// x is LDS-stationary. Static 64 KB LDS so the allocator sees true occupancy
// (2 blocks/CU -> 4 waves/SIMD -> 128-VGPR budget); __launch_bounds__(512,2)
// (arg2 = blocks/CU, CUDA-style per r2/r3 evidence) caps regs at 128.
// 9 barriers/block, none coupled to weight staging.
__global__ __launch_bounds__(512, 2) void fused_mlp(
    const float* __restrict__ h,
    const int* __restrict__ src,
    const int* __restrict__ dst,
    const f16_t* __restrict__ wks,
    const float* __restrict__ b1, const float* __restrict__ g1, const float* __restrict__ be1,
    const float* __restrict__ b2, const float* __restrict__ g2, const float* __restrict__ be2,
    const float* __restrict__ w3, const float* __restrict__ b3,
    float* __restrict__ out, int E, int nrows) {
  __shared__ __attribute__((aligned(16))) f16_t xbuf[32768];  // 64 KB exactly
  // LN1 stats alias upper 32 KB (x0 only occupies lower 32 KB):
  float* s1sum = (float*)(xbuf + 16384);        // [4][128]
  float* s1sq  = (float*)(xbuf + 16384) + 512;  // [4][128]
  float* s1mean = (float*)(xbuf + 16384) + 1024;  // [128]
  float* s1rstd = (float*)(xbuf + 16384) + 1152;  // [128]
  // LN2 stats alias base (x1 dead after GEMM2 + barrier):
  float* s2sum = (float*)xbuf;
  float* s2sq  = (float*)xbuf + 512;
  float* s2mean = (float*)xbuf + 1024;
  float* s2rstd = (float*)xbuf + 1152;

  const int t = threadIdx.x;
  const int ebase = blockIdx.x * 128;

  // ---------- gather: x0[m][k] = h[src][k]*h[dst][k], fp16, swizzled stride-128 ----------
  {
    const int m = t >> 2;          // edge 0..127
    const int kq = (t & 3) * 32;   // k-offset
    const int e = ebase + m;
    f16_t* xrow = xbuf + m * 128;
    if (e < E) {
      int si = src[e], di = dst[e];
      si = ((unsigned)si < (unsigned)nrows) ? si : 0;
      di = ((unsigned)di < (unsigned)nrows) ? di : 0;
      const float* hs = h + (long long)si * 128 + kq;
      const float* hd = h + (long long)di * 128 + kq;
#pragma unroll
      for (int i = 0; i < 4; ++i) {
        const float4 a0 = *(const float4*)(hs + i * 8);
        const float4 a1 = *(const float4*)(hs + i * 8 + 4);
        const float4 c0 = *(const float4*)(hd + i * 8);
        const float4 c1 = *(const float4*)(hd + i * 8 + 4);
        union { f16x8 v8; f16x2 v2[4]; } u;
        u.v2[0] = pk2(a0.x * c0.x, a0.y * c0.y);
        u.v2[1] = pk2(a0.z * c0.z, a0.w * c0.w);
        u.v2[2] = pk2(a1.x * c1.x, a1.y * c1.y);
        u.v2[3] = pk2(a1.z * c1.z, a1.w * c1.w);
        const int g = (((kq >> 3) + i) ^ m) & 15;
        *(f16x8*)(xrow + g * 8) = u.v8;
      }
    } else {
      f16x8 z = {};
#pragma unroll
      for (int i = 0; i < 4; ++i) {
        const int g = (((kq >> 3) + i) ^ m) & 15;
        *(f16x8*)(xrow + g * 8) = z;
      }
    }
  }
  __syncthreads();  // b1: x0 ready

  const int lane = t & 63;
  const int wave = t >> 6;
  const int wf = wave & 3;   // feat-row: 64 feats
  const int ec = wave >> 2;  // edge-col: 64 edges
  const int c = lane & 15;
  const int q = lane >> 4;
  const int featBase = wf * 64;
  int eidx[4];
#pragma unroll
  for (int n = 0; n < 4; ++n) eidx[n] = ec * 64 + n * 16 + c;

  // ---------- GEMM1: K=128, weights direct from global (coalesced frags) ----------
  const f16_t* wb1 = wks + (wf * 256 + lane) * 8;
  f32x4 acc[4][4];
#pragma unroll
  for (int msf = 0; msf < 4; ++msf)
#pragma unroll
    for (int n = 0; n < 4; ++n) acc[msf][n] = (f32x4){0.f, 0.f, 0.f, 0.f};

#pragma unroll 2
  for (int kc = 0; kc < 4; ++kc) {
    f16x8 af[4], bf[4];
#pragma unroll
    for (int msf = 0; msf < 4; ++msf)
      af[msf] = *(const f16x8*)(wb1 + kc * 8192 + msf * 512);
    const int gp = ((kc * 4 + q) ^ c) & 15;
#pragma unroll
    for (int n = 0; n < 4; ++n)
      bf[n] = *(const f16x8*)(xbuf + eidx[n] * 128 + gp * 8);
#pragma unroll
    for (int msf = 0; msf < 4; ++msf)
#pragma unroll
      for (int n = 0; n < 4; ++n)
        acc[msf][n] = __builtin_amdgcn_mfma_f32_16x16x32_f16(af[msf], bf[n], acc[msf][n], 0, 0, 0);
  }

  // ---------- LN1 stats (upper-LDS region; x0 untouched) ----------
  {
    float s[4] = {0.f, 0.f, 0.f, 0.f}, sq[4] = {0.f, 0.f, 0.f, 0.f};
#pragma unroll
    for (int msf = 0; msf < 4; ++msf) {
      const float4 bv = *(const float4*)(b1 + featBase + msf * 16 + q * 4);
#pragma unroll
      for (int r = 0; r < 4; ++r) {
        const float b = COMP(bv, r);
#pragma unroll
        for (int n = 0; n < 4; ++n) {
          float v = acc[msf][n][r] + b;
          acc[msf][n][r] = v;
          s[n] += v; sq[n] += v * v;
        }
      }
    }
#pragma unroll
    for (int n = 0; n < 4; ++n) {
      s[n] += __shfl_xor(s[n], 16, 64);  s[n] += __shfl_xor(s[n], 32, 64);
      sq[n] += __shfl_xor(sq[n], 16, 64); sq[n] += __shfl_xor(sq[n], 32, 64);
    }
    if (q == 0) {
#pragma unroll
      for (int n = 0; n < 4; ++n) {
        s1sum[wf * 128 + eidx[n]] = s[n];
        s1sq[wf * 128 + eidx[n]] = sq[n];
      }
    }
  }
  __syncthreads();  // b2: stats written; all GEMM1 x0 reads done
  if (t < 128) {
    float s = s1sum[t] + s1sum[128 + t] + s1sum[256 + t] + s1sum[384 + t];
    float sq = s1sq[t] + s1sq[128 + t] + s1sq[256 + t] + s1sq[384 + t];
    float mu = s * (1.f / 256.f);
    float var = sq * (1.f / 256.f) - mu * mu;
    s1mean[t] = mu;
    s1rstd[t] = rsqrtf(var + 1e-5f);
  }
  __syncthreads();  // b3: mean/rstd ready

  // ---------- LN1 normalize + ReLU -> hv regs; then write x1 after protect barrier ----------
  f16x4 hv[4][4];
  {
    float mu[4], rs[4];
#pragma unroll
    for (int n = 0; n < 4; ++n) { mu[n] = s1mean[eidx[n]]; rs[n] = s1rstd[eidx[n]]; }
#pragma unroll
    for (int msf = 0; msf < 4; ++msf) {
      const float4 gv = *(const float4*)(g1 + featBase + msf * 16 + q * 4);
      const float4 bev = *(const float4*)(be1 + featBase + msf * 16 + q * 4);
#pragma unroll
      for (int n = 0; n < 4; ++n) {
        float v0 = fmaxf((acc[msf][n][0] - mu[n]) * rs[n] * gv.x + bev.x, 0.f);
        float v1 = fmaxf((acc[msf][n][1] - mu[n]) * rs[n] * gv.y + bev.y, 0.f);
        float v2 = fmaxf((acc[msf][n][2] - mu[n]) * rs[n] * gv.z + bev.z, 0.f);
        float v3 = fmaxf((acc[msf][n][3] - mu[n]) * rs[n] * gv.w + bev.w, 0.f);
        union { f16x4 v4; f16x2 v2p[2]; } u;
        u.v2p[0] = pk2(v0, v1); u.v2p[1] = pk2(v2, v3);
        hv[msf][n] = u.v4;
      }
    }
  }
  __syncthreads();  // b4: stats consumed everywhere; xbuf fully writable
  {
    const int j0 = (q & 1) * 4;
#pragma unroll
    for (int msf = 0; msf < 4; ++msf) {
      const int g = wf * 8 + msf * 2 + (q >> 1);  // feat 16B-group 0..31
      const int gp = (g & 16) | ((g ^ c) & 15);
#pragma unroll
      for (int n = 0; n < 4; ++n)
        *(f16x4*)(xbuf + eidx[n] * 256 + gp * 8 + j0) = hv[msf][n];
    }
  }
  __syncthreads();  // b5: x1 visible

  // ---------- GEMM2: K=256, weights direct from global ----------
  const f16_t* wb2 = wks + 32768 + (wf * 256 + lane) * 8;
  f32x4 acc2[4][4];
#pragma unroll
  for (int msf = 0; msf < 4; ++msf)
#pragma unroll
    for (int n = 0; n < 4; ++n) acc2[msf][n] = (f32x4){0.f, 0.f, 0.f, 0.f};

#pragma unroll 2
  for (int kc = 0; kc < 8; ++kc) {
    f16x8 af[4], bf[4];
#pragma unroll
    for (int msf = 0; msf < 4; ++msf)
      af[msf] = *(const f16x8*)(wb2 + kc * 8192 + msf * 512);
    const int g = kc * 4 + q;  // 0..31
    const int gp = (g & 16) | ((g ^ c) & 15);
#pragma unroll
    for (int n = 0; n < 4; ++n)
      bf[n] = *(const f16x8*)(xbuf + eidx[n] * 256 + gp * 8);
#pragma unroll
    for (int msf = 0; msf < 4; ++msf)
#pragma unroll
      for (int n = 0; n < 4; ++n)
        acc2[msf][n] = __builtin_amdgcn_mfma_f32_16x16x32_f16(af[msf], bf[n], acc2[msf][n], 0, 0, 0);
  }
  __syncthreads();  // b6: all x1 reads done; base stats region writable

  // ---------- LN2 stats ----------
  {
    float s[4] = {0.f, 0.f, 0.f, 0.f}, sq[4] = {0.f, 0.f, 0.f, 0.f};
#pragma unroll
    for (int msf = 0; msf < 4; ++msf) {
      const float4 bv = *(const float4*)(b2 + featBase + msf * 16 + q * 4);
#pragma unroll
      for (int r = 0; r < 4; ++r) {
        const float b = COMP(bv, r);
#pragma unroll
        for (int n = 0; n < 4; ++n) {
          float v = acc2[msf][n][r] + b;
          acc2[msf][n][r] = v;
          s[n] += v; sq[n] += v * v;
        }
      }
    }
#pragma unroll
    for (int n = 0; n < 4; ++n) {
      s[n] += __shfl_xor(s[n], 16, 64);  s[n] += __shfl_xor(s[n], 32, 64);
      sq[n] += __shfl_xor(sq[n], 16, 64); sq[n] += __shfl_xor(sq[n], 32, 64);
    }
    if (q == 0) {
#pragma unroll
      for (int n = 0; n < 4; ++n) {
        s2sum[wf * 128 + eidx[n]] = s[n];
        s2sq[wf * 128 + eidx[n]] = sq[n];
      }
    }
  }
  __syncthreads();  // b7
  if (t < 128) {
    float s = s2sum[t] + s2sum[128 + t] + s2sum[256 + t] + s2sum[384 + t];
    float sq = s2sq[t] + s2sq[128 + t] + s2sq[256 + t] + s2sq[384 + t];
    float mu = s * (1.f / 256.f);
    float var = sq * (1.f / 256.f) - mu * mu;
    s2mean[t] = mu;
    s2rstd[t] = rsqrtf(var + 1e-5f);
  }
  __syncthreads();  // b8

  // ---------- LN2 normalize + ReLU + dot(W3) ----------
  {
    float mu[4], rs[4], p[4] = {0.f, 0.f, 0.f, 0.f};
#pragma unroll
    for (int n = 0; n < 4; ++n) { mu[n] = s2mean[eidx[n]]; rs[n] = s2rstd[eidx[n]]; }
#pragma unroll
    for (int msf = 0; msf < 4; ++msf) {
      const float4 gv = *(const float4*)(g2 + featBase + msf * 16 + q * 4);
      const float4 bev = *(const float4*)(be2 + featBase + msf * 16 + q * 4);
      const float4 wv = *(const float4*)(w3 + featBase + msf * 16 + q * 4);
#pragma unroll
      for (int r = 0; r < 4; ++r) {
        const float gr = COMP(gv, r), ber = COMP(bev, r), wr = COMP(wv, r);
#pragma unroll
        for (int n = 0; n < 4; ++n) {
          float v = fmaxf((acc2[msf][n][r] - mu[n]) * rs[n] * gr + ber, 0.f);
          p[n] = fmaf(v, wr, p[n]);
        }
      }
    }
#pragma unroll
    for (int n = 0; n < 4; ++n) {
      p[n] += __shfl_xor(p[n], 16, 64);
      p[n] += __shfl_xor(p[n], 32, 64);
    }
    if (q == 0) {
#pragma unroll
      for (int n = 0; n < 4; ++n) s2sum[wf * 128 + eidx[n]] = p[n];  // disjoint from s2mean
    }
  }
  __syncthreads();  // b9
  if (t < 128) {
    int e = ebase + t;
    if (e < E) {
      float sres = s2sum[t] + s2sum[128 + t] + s2sum[256 + t] + s2sum[384 + t] + b3[0];
      out[e] = 1.f / (1.f + __expf(-sres));
    }
  }
}

extern "C" void kernel_launch(void* const* d_in, const int* in_sizes, int n_in,
                              void* d_out, int out_size, void* d_ws, size_t ws_size,
                              hipStream_t stream) {
  const float* h = (const float*)d_in[0];
  const int* src = (const int*)d_in[1];
  const int* dst = (const int*)d_in[2];
  const float* W1 = (const float*)d_in[3];
  const float* b1 = (const float*)d_in[4];
  const float* g1 = (const float*)d_in[5];
  const float* be1 = (const float*)d_in[6];
  const float* W2 = (const float*)d_in[7];
  const float* b2 = (const float*)d_in[8];
  const float* g2 = (const float*)d_in[9];
  const float* be2 = (const float*)d_in[10];
  const float* W3 = (const float*)d_in[11];
  const float* b3 = (const float*)d_in[12];
  float* out = (float*)d_out;
  const int E = in_sizes[1];
  const int nrows = in_sizes[0] / 128;
  f16_t* wks = (f16_t*)d_ws;  // 98304 f16 = 196608 bytes

  wconv<<<256, 256, 0, stream>>>(W1, W2, wks);
  const int tiles = (E + 127) / 128;
  fused_mlp<<<tiles, 512, 0, stream>>>(h, src, dst, wks, b1, g1, be1,
                                       b2, g2, be2, W3, b3, out, E, nrows);
}